// Round 9
// baseline (33.862 us; speedup 1.0000x reference)
//
#include <hip/hip_runtime.h>
#include <math.h>

// No-LDS pure-streaming kernel. Each FIR thread computes 4 consecutive
// complex outputs of one row directly from global memory:
//   - 4 aligned float4 loads for the 8 taps (cof row = 64 B, 64B-aligned)
//   - 11 float2 loads for the sliding window x[i0-7 .. i0+3]
//     (adjacent threads overlap by 7 -> L1 serves the reuse)
//   - 128 FMA -> 2 aligned float4 stores
// No LDS, no barrier, no staging pass; threads fully independent -> max TLP.
// Edge threads (p in {0,1,141,142,143} of 144 per row) use a predicated
// clamped-load path. The 64-point tap DFT rides in the same grid (blocks
// >= FIRB), one k per thread, taps L1-broadcast across 64 threads.
//
// Problem constants:
//   N=4096, P=4 -> B = 16384 rows
//   SMK = 567, L = 8, OUTLEN = 574, M = 64
// Output layout (flat): out (B,574,2) f32, then H (B,64,2) f32.
//
// Geometry: 144 FIR threads/row (thread p -> outputs 4p .. 4p+3; p=143 only
// 572,573). FIRB = 16384*144/256 = 9216 blocks; H: 16384*64/256 = 4096.

#define B_ROWS 16384
#define SMK    567
#define LTAPS  8
#define OUTLEN 574
#define MFFT   64
#define TPR    144
#define FIRB   9216   // B_ROWS*TPR/256
#define HB     4096   // B_ROWS*MFFT/256

__global__ __launch_bounds__(256) void channel_kernel(
    const float2* __restrict__ x,    // (B, SMK)
    const float2* __restrict__ cof,  // (B, LTAPS)
    float2* __restrict__ out,        // (B, OUTLEN)
    float2* __restrict__ H)          // (B, MFFT)
{
    const int gid = blockIdx.x;
    const int tid = threadIdx.x;

    if (gid < FIRB) {
        const int gt  = gid * 256 + tid;
        const int row = gt / TPR;            // const-div -> magic mul
        const int p   = gt - row * TPR;
        const int i0  = 4 * p;

        const float2* __restrict__ xrow = x + (size_t)row * SMK;

        // Taps: cof row is exactly 64 B and 64B-aligned -> 4 float4 loads.
        const float4* __restrict__ c4 = (const float4*)(cof + (size_t)row * LTAPS);
        float4 h01 = c4[0], h23 = c4[1], h45 = c4[2], h67 = c4[3];
        float hr[LTAPS] = {h01.x, h01.z, h23.x, h23.z, h45.x, h45.z, h67.x, h67.z};
        float hi[LTAPS] = {h01.y, h01.w, h23.y, h23.w, h45.y, h45.w, h67.y, h67.w};

        // Window w[m] = x[i0-7+m], m = 0..10.
        float2 w[11];
        if (p >= 2 && p <= 140) {
            #pragma unroll
            for (int m = 0; m < 11; ++m) w[m] = xrow[i0 - 7 + m];
        } else {
            #pragma unroll
            for (int m = 0; m < 11; ++m) {
                int idx = i0 - 7 + m;
                w[m] = (idx >= 0 && idx < SMK) ? xrow[idx]
                                               : make_float2(0.0f, 0.0f);
            }
        }

        // out[i0+q] = sum_j h[j] * x[i0+q-j] = sum_j h[j] * w[7+q-j]
        float sr[4] = {0.f, 0.f, 0.f, 0.f};
        float si[4] = {0.f, 0.f, 0.f, 0.f};
        #pragma unroll
        for (int j = 0; j < LTAPS; ++j) {
            #pragma unroll
            for (int q = 0; q < 4; ++q) {
                float2 xv = w[7 + q - j];   // static index after unroll
                sr[q] = fmaf(hr[j], xv.x, sr[q]);
                sr[q] = fmaf(-hi[j], xv.y, sr[q]);
                si[q] = fmaf(hr[j], xv.y, si[q]);
                si[q] = fmaf(hi[j], xv.x, si[q]);
            }
        }

        // Stores: out row base is 16B-aligned (4592 B stride), i0*8 is 32B mult.
        float4* __restrict__ o4 = (float4*)(out + (size_t)row * OUTLEN + i0);
        o4[0] = make_float4(sr[0], si[0], sr[1], si[1]);
        if (p < TPR - 1) {                   // p=143 owns only outputs 572,573
            o4[1] = make_float4(sr[2], si[2], sr[3], si[3]);
        }
    } else {
        // 64-point DFT of the 8 taps: one k per thread, 64 threads per row.
        const int ht  = (gid - FIRB) * 256 + tid;
        const int row = ht >> 6;
        const int k   = ht & (MFFT - 1);

        const float4* __restrict__ c4 = (const float4*)(cof + (size_t)row * LTAPS);
        float4 h01 = c4[0], h23 = c4[1], h45 = c4[2], h67 = c4[3];
        float hr[LTAPS] = {h01.x, h01.z, h23.x, h23.z, h45.x, h45.z, h67.x, h67.z};
        float hi[LTAPS] = {h01.y, h01.w, h23.y, h23.w, h45.y, h45.w, h67.y, h67.w};

        float accr = 0.0f, acci = 0.0f;
        #pragma unroll
        for (int l = 0; l < LTAPS; ++l) {
            int t = (k * l) & (MFFT - 1);
            float ang = -6.2831853071795864769f * (float)t * (1.0f / (float)MFFT);
            float sn, cs;
            __sincosf(ang, &sn, &cs);
            accr = fmaf(hr[l], cs, accr);
            accr = fmaf(-hi[l], sn, accr);
            acci = fmaf(hr[l], sn, acci);
            acci = fmaf(hi[l], cs, acci);
        }
        H[(size_t)row * MFFT + k] = make_float2(accr, acci);
    }
}

extern "C" void kernel_launch(void* const* d_in, const int* in_sizes, int n_in,
                              void* d_out, int out_size, void* d_ws, size_t ws_size,
                              hipStream_t stream) {
    const float2* x   = (const float2*)d_in[0];  // (N,P,SMK,2) f32
    const float2* cof = (const float2*)d_in[1];  // (N,P,L,2)  f32
    float* outf = (float*)d_out;

    float2* conv_out = (float2*)outf;                                  // (B, 574)
    float2* H        = (float2*)(outf + (size_t)B_ROWS * OUTLEN * 2);  // (B, 64)

    channel_kernel<<<FIRB + HB, 256, 0, stream>>>(x, cof, conv_out, H);
}